// Round 1
// baseline (353.928 us; speedup 1.0000x reference)
//
#include <hip/hip_runtime.h>
#include <math.h>

#define B_   256
#define IN_  512
#define C_   4
#define M_   6
#define K_   64
#define S1_  255
#define S2_  63
#define CHUNK 32

#define LMIN_ (-6.906754778648554f)
#define LMAX_ ( 6.906754778648554f)
#define LR_   0.001f
#define WCLIP_ 5.0f

__device__ __forceinline__ float clampf(float v, float lo, float hi) {
    return fminf(fmaxf(v, lo), hi);
}

__global__ void init_kernel(const float* __restrict__ x,
                            const float* __restrict__ bias1,
                            const float* __restrict__ bias2,
                            float* __restrict__ l0,
                            float* __restrict__ out1t,
                            float* __restrict__ out2t) {
    int gid = blockIdx.x * blockDim.x + threadIdx.x;  // 0..131071
    if (gid < B_ * IN_) {
        int i = gid & (IN_ - 1);
        float xv = x[gid];
        xv = clampf(xv, 0.001f, 0.999f);
        float v = (i == 0) ? 0.0f : logf(xv / (1.0f - xv));
        l0[gid] = v;
    }
    if (gid < C_ * B_) {
        int c = gid >> 8;  // B_=256
        out1t[(size_t)gid * (S1_ + 1)] = bias1[c];
        out2t[(size_t)gid * (S2_ + 1)] = bias2[c];
    }
}

// One block per (c,s). 256 threads; thread = batch row b.
__global__ __launch_bounds__(256) void layer_kernel(
    const float* __restrict__ x,      // B x IN (context, always x)
    const float* __restrict__ lg,     // lg[c*lg_sc + b*lg_sb + i]
    long lg_sc, long lg_sb,
    const int* __restrict__ target,   // B
    const float* __restrict__ cmaps,  // C,S,M,IN
    const float* __restrict__ w,      // C,S,K,Din
    float* __restrict__ nw,           // C,S,K,Din  (in d_out)
    float* __restrict__ onext,        // [c][b][S+1] next-lg, or logits[b][c] if last
    int S, int Din, int is_last)
{
    __shared__ float xt[CHUNK][B_ + 1];   // transposed chunk of x / lg
    __shared__ float wl[K_][CHUNK + 1];   // w chunk
    __shared__ float diff_s[B_];
    __shared__ int   winner[K_];

    const int bx  = blockIdx.x;
    const int c   = bx / S;
    const int s   = bx % S;
    const int tid = threadIdx.x;
    const int b   = tid;

    if (tid < K_) winner[tid] = -1;

    // ---------------- Phase A: dist = cmaps[c,s,m,:] . x[b,:]  -> idx ----------------
    const float* cmp = cmaps + ((size_t)(c * S + s) * M_) * IN_;
    float acc[M_];
#pragma unroll
    for (int m = 0; m < M_; ++m) acc[m] = 0.0f;

    for (int k0 = 0; k0 < IN_; k0 += CHUNK) {
        __syncthreads();
#pragma unroll
        for (int j = 0; j < 8; ++j) {               // 256*32 elems = 2048 float4
            int f   = tid + 256 * j;
            int row = f >> 3;                        // 8 quads per row-chunk
            int kq  = (f & 7) << 2;
            const float4 v = *(const float4*)(x + (size_t)row * IN_ + k0 + kq);
            xt[kq + 0][row] = v.x;
            xt[kq + 1][row] = v.y;
            xt[kq + 2][row] = v.z;
            xt[kq + 3][row] = v.w;
        }
        __syncthreads();
#pragma unroll
        for (int kk = 0; kk < CHUNK; ++kk) {
            float xv = xt[kk][b];
#pragma unroll
            for (int m = 0; m < M_; ++m)
                acc[m] = fmaf(cmp[(size_t)m * IN_ + k0 + kk], xv, acc[m]);  // cmp: wave-uniform -> s_load
        }
    }
    int myidx = 0;
#pragma unroll
    for (int m = 0; m < M_; ++m) myidx |= (acc[m] > 0.0f) ? (1 << m) : 0;

    atomicMax(&winner[myidx], b);   // last-b-wins == max b

    // ---------------- Phase B: out = clip( w[c,s,idx[b],:] . lg[b,:,c] ) ----------------
    const float* wp  = w  + (size_t)(c * S + s) * K_ * Din;
    const float* lgc = lg + (size_t)c * lg_sc;
    float acc2 = 0.0f;
    for (int k0 = 0; k0 < Din; k0 += CHUNK) {
        __syncthreads();
#pragma unroll
        for (int j = 0; j < 8; ++j) {               // stage lg chunk transposed
            int f   = tid + 256 * j;
            int row = f >> 3;
            int kq  = (f & 7) << 2;
            const float4 v = *(const float4*)(lgc + (size_t)row * lg_sb + k0 + kq);
            xt[kq + 0][row] = v.x;
            xt[kq + 1][row] = v.y;
            xt[kq + 2][row] = v.z;
            xt[kq + 3][row] = v.w;
        }
#pragma unroll
        for (int j = 0; j < 2; ++j) {               // stage w chunk: 64 rows x 32 k
            int f   = tid + 256 * j;
            int row = f >> 3;
            int kq  = (f & 7) << 2;
            const float4 v = *(const float4*)(wp + (size_t)row * Din + k0 + kq);
            wl[row][kq + 0] = v.x;
            wl[row][kq + 1] = v.y;
            wl[row][kq + 2] = v.z;
            wl[row][kq + 3] = v.w;
        }
        __syncthreads();
#pragma unroll
        for (int kk = 0; kk < CHUNK; ++kk)
            acc2 = fmaf(wl[myidx][kk], xt[kk][b], acc2);
    }

    float outv = clampf(acc2, LMIN_, LMAX_);
    if (is_last) {
        onext[(size_t)b * C_ + c] = outv;                              // logits[b][c]
    } else {
        onext[((size_t)c * B_ + b) * (size_t)(S + 1) + (s + 1)] = outv; // out_t[c][b][s+1]
    }
    float tg = (target[b] == c) ? 1.0f : 0.0f;
    diff_s[b] = 1.0f / (1.0f + expf(-outv)) - tg;
    __syncthreads();   // winner + diff_s final

    // ---------------- Phase D: nw = clip(w - LR*diff[b*]*lg[b*,:], +-5) ----------------
    float* nwp = nw + (size_t)(c * S + s) * K_ * Din;
    const int qpr   = Din >> 2;       // quads per bucket row
    const int quads = K_ * qpr;
    for (int q = tid; q < quads; q += 256) {
        int row = q / qpr;
        int col = (q - row * qpr) << 2;
        float4 wv = *(const float4*)(wp + (size_t)row * Din + col);
        int bw = winner[row];
        if (bw >= 0) {
            float d = LR_ * diff_s[bw];
            const float4 lv = *(const float4*)(lgc + (size_t)bw * lg_sb + col);
            wv.x = clampf(wv.x - d * lv.x, -WCLIP_, WCLIP_);
            wv.y = clampf(wv.y - d * lv.y, -WCLIP_, WCLIP_);
            wv.z = clampf(wv.z - d * lv.z, -WCLIP_, WCLIP_);
            wv.w = clampf(wv.w - d * lv.w, -WCLIP_, WCLIP_);
        }
        *(float4*)(nwp + (size_t)row * Din + col) = wv;
    }
}

extern "C" void kernel_launch(void* const* d_in, const int* in_sizes, int n_in,
                              void* d_out, int out_size, void* d_ws, size_t ws_size,
                              hipStream_t stream) {
    const float* x      = (const float*)d_in[0];
    const int*   target = (const int*)  d_in[1];
    const float* cmaps1 = (const float*)d_in[2];
    const float* w1     = (const float*)d_in[3];
    const float* bias1  = (const float*)d_in[4];
    const float* cmaps2 = (const float*)d_in[5];
    const float* w2     = (const float*)d_in[6];
    const float* bias2  = (const float*)d_in[7];
    const float* cmaps3 = (const float*)d_in[8];
    const float* w3     = (const float*)d_in[9];
    float* out = (float*)d_out;

    float* l0    = (float*)d_ws;                          // B*IN
    float* out1t = l0 + (size_t)B_ * IN_;                 // C*B*(S1+1)
    float* out2t = out1t + (size_t)C_ * B_ * (S1_ + 1);   // C*B*(S2+1)

    float* logits = out;
    float* nw1 = out + (size_t)B_ * C_;
    float* nw2 = nw1 + (size_t)C_ * S1_ * K_ * IN_;
    float* nw3 = nw2 + (size_t)C_ * S2_ * K_ * (S1_ + 1);

    init_kernel<<<dim3((B_ * IN_) / 256), dim3(256), 0, stream>>>(x, bias1, bias2, l0, out1t, out2t);

    // layer 1: lg = l0 (broadcast over c): stride_c = 0, stride_b = IN
    layer_kernel<<<dim3(C_ * S1_), dim3(256), 0, stream>>>(
        x, l0, 0L, (long)IN_, target, cmaps1, w1, nw1, out1t, S1_, IN_, 0);

    // layer 2: lg = out1t [c][b][S1+1]
    layer_kernel<<<dim3(C_ * S2_), dim3(256), 0, stream>>>(
        x, out1t, (long)B_ * (S1_ + 1), (long)(S1_ + 1), target, cmaps2, w2, nw2, out2t, S2_, S1_ + 1, 0);

    // layer 3: lg = out2t [c][b][S2+1]; writes logits
    layer_kernel<<<dim3(C_), dim3(256), 0, stream>>>(
        x, out2t, (long)B_ * (S2_ + 1), (long)(S2_ + 1), target, cmaps3, w3, nw3, logits, 1, S2_ + 1, 1);
}

// Round 2
// 204.291 us; speedup vs baseline: 1.7325x; 1.7325x over previous
//
#include <hip/hip_runtime.h>
#include <math.h>

#define B_   256
#define IN_  512
#define C_   4
#define M_   6
#define K_   64
#define S1_  255
#define S2_  63
#define WCH  64    // w-chunk width (k per chunk)

#define LMIN_ (-6.906754778648554f)
#define LMAX_ ( 6.906754778648554f)
#define LR_   0.001f
#define WCLIP_ 5.0f

__device__ __forceinline__ float clampf(float v, float lo, float hi) {
    return fminf(fmaxf(v, lo), hi);
}

// One-time prep: xT[i][b], l0[b][i], l0T[i][b]. 32x32 tiles, 128 blocks.
__global__ __launch_bounds__(256) void prep_kernel(const float* __restrict__ x,
                                                   float* __restrict__ xT,
                                                   float* __restrict__ l0,
                                                   float* __restrict__ l0T) {
    __shared__ float tx_[32][33];
    __shared__ float tl_[32][33];
    const int i0 = (blockIdx.x & 15) * 32;   // IN/32 = 16 tiles
    const int b0 = (blockIdx.x >> 4) * 32;   // B/32  = 8 tiles
    const int tx = threadIdx.x & 31;
    const int ty = threadIdx.x >> 5;         // 0..7
#pragma unroll
    for (int r = 0; r < 4; ++r) {
        int bb = b0 + ty + 8 * r;
        int ii = i0 + tx;
        float xv = x[(size_t)bb * IN_ + ii];
        float xc = clampf(xv, 0.001f, 0.999f);
        float lv = (ii == 0) ? 0.0f : logf(xc / (1.0f - xc));
        l0[(size_t)bb * IN_ + ii] = lv;
        tx_[ty + 8 * r][tx] = xv;
        tl_[ty + 8 * r][tx] = lv;
    }
    __syncthreads();
#pragma unroll
    for (int r = 0; r < 4; ++r) {
        int ii = i0 + ty + 8 * r;
        int bb = b0 + tx;
        xT[(size_t)ii * B_ + bb]  = tx_[tx][ty + 8 * r];
        l0T[(size_t)ii * B_ + bb] = tl_[tx][ty + 8 * r];
    }
}

// One block per (c,s); 256 threads; thread = batch row b.
__global__ __launch_bounds__(256) void layer_kernel(
    const float* __restrict__ xT,      // [IN][B] context transposed
    const float* __restrict__ lgT,     // lgT[c*lgT_sc + k*B + b]
    const float* __restrict__ lgRM,    // lg[c*lg_sc + b*Din + k]
    long lgT_sc, long lg_sc,
    const int* __restrict__ target,
    const float* __restrict__ cmaps,   // [C][S][M][IN]
    const float* __restrict__ w,       // [C][S][K][Din]
    float* __restrict__ nw,            // [C][S][K][Din]
    float* __restrict__ onextT,        // [c][S+1][b]  (null if last)
    float* __restrict__ onextRM,       // [c][b][S+1], or logits[b][c] if last
    const float* __restrict__ bias,    // [1,1,C] or null
    int S, int Din, int is_last)
{
    __shared__ float wl[2][K_][WCH + 1];
    __shared__ float diff_s[B_];
    __shared__ int   winner[K_];

    const int c   = blockIdx.x / S;
    const int s   = blockIdx.x % S;
    const int tid = threadIdx.x;
    const int b   = tid;

    if (tid < K_) winner[tid] = -1;

    // ---------- Phase A: dist = cmaps[c,s,m,:] . x[b,:] -> idx ----------
    const float* cmp = cmaps + (size_t)(c * S + s) * M_ * IN_;
    float acc[M_];
#pragma unroll
    for (int m = 0; m < M_; ++m) acc[m] = 0.0f;

    for (int k = 0; k < IN_; k += 8) {
        float xv[8];
#pragma unroll
        for (int j = 0; j < 8; ++j) xv[j] = xT[(size_t)(k + j) * B_ + b];  // coalesced, L2-hot
#pragma unroll
        for (int j = 0; j < 8; ++j)
#pragma unroll
            for (int m = 0; m < M_; ++m)
                acc[m] = fmaf(cmp[(size_t)m * IN_ + k + j], xv[j], acc[m]); // uniform -> s_load
    }
    int myidx = 0;
#pragma unroll
    for (int m = 0; m < M_; ++m) myidx |= (acc[m] > 0.0f) ? (1 << m) : 0;

    // ---------- Phase B: out = clip( w[c,s,idx[b],:] . lg[b,:,c] ) ----------
    const float* wp   = w   + (size_t)(c * S + s) * K_ * Din;
    const float* lgTc = lgT + (size_t)c * lgT_sc;
    const int NT = Din / WCH;

    // stage chunk t into buffer buf: 64 rows x 64 cols = 1024 float4 = 4/thread
#define STAGE(buf, t)                                                          \
    {                                                                          \
        const float* src = wp + (size_t)(t) * WCH;                             \
        _Pragma("unroll")                                                      \
        for (int j = 0; j < 4; ++j) {                                          \
            int f   = tid + 256 * j;                                           \
            int row = f >> 4;                                                  \
            int kq  = (f & 15) << 2;                                           \
            const float4 v = *(const float4*)(src + (size_t)row * Din + kq);   \
            wl[buf][row][kq + 0] = v.x;                                        \
            wl[buf][row][kq + 1] = v.y;                                        \
            wl[buf][row][kq + 2] = v.z;                                        \
            wl[buf][row][kq + 3] = v.w;                                        \
        }                                                                      \
    }

    STAGE(0, 0)
    __syncthreads();                 // covers winner-init visibility too
    atomicMax(&winner[myidx], b);    // last-b-wins == max b

    float dot = 0.0f;
    for (int t = 0; t < NT; ++t) {
        const int cur = t & 1;
        if (t + 1 < NT) STAGE(cur ^ 1, t + 1)
#pragma unroll 16
        for (int kk = 0; kk < WCH; ++kk)
            dot = fmaf(wl[cur][myidx][kk], lgTc[(size_t)(t * WCH + kk) * B_ + b], dot);
        __syncthreads();
    }

    float outv = clampf(dot, LMIN_, LMAX_);
    if (is_last) {
        onextRM[(size_t)b * C_ + c] = outv;                          // logits[b][c]
    } else {
        onextT[((size_t)c * (S + 1) + (s + 1)) * B_ + b] = outv;     // coalesced
        onextRM[((size_t)c * B_ + b) * (size_t)(S + 1) + (s + 1)] = outv;
        if (s == 0) {
            float bv = bias[c];
            onextT[((size_t)c * (S + 1)) * B_ + b] = bv;
            onextRM[((size_t)c * B_ + b) * (size_t)(S + 1)] = bv;
        }
    }
    float tg = (target[b] == c) ? 1.0f : 0.0f;
    diff_s[b] = 1.0f / (1.0f + expf(-outv)) - tg;
    __syncthreads();

    // ---------- Phase D: nw = clip(w - LR*diff[b*]*lg[b*,:], +-WCLIP) ----------
    float* nwp = nw + (size_t)(c * S + s) * K_ * Din;
    const float* lgc = lgRM + (size_t)c * lg_sc;
    const int qpr   = Din >> 2;            // float4 per row (pow2)
    const int qprs  = (Din == 512) ? 7 : (Din == 256) ? 6 : 4;
    const int quads = K_ * qpr;
    for (int q = tid; q < quads; q += 256) {
        int row = q >> qprs;
        int col = (q & (qpr - 1)) << 2;
        float4 wv = *(const float4*)(wp + (size_t)row * Din + col);
        int bw = winner[row];
        if (bw >= 0) {
            float d = LR_ * diff_s[bw];
            const float4 lv = *(const float4*)(lgc + (size_t)bw * Din + col);
            wv.x = clampf(wv.x - d * lv.x, -WCLIP_, WCLIP_);
            wv.y = clampf(wv.y - d * lv.y, -WCLIP_, WCLIP_);
            wv.z = clampf(wv.z - d * lv.z, -WCLIP_, WCLIP_);
            wv.w = clampf(wv.w - d * lv.w, -WCLIP_, WCLIP_);
        }
        *(float4*)(nwp + (size_t)row * Din + col) = wv;
    }
#undef STAGE
}

extern "C" void kernel_launch(void* const* d_in, const int* in_sizes, int n_in,
                              void* d_out, int out_size, void* d_ws, size_t ws_size,
                              hipStream_t stream) {
    const float* x      = (const float*)d_in[0];
    const int*   target = (const int*)  d_in[1];
    const float* cmaps1 = (const float*)d_in[2];
    const float* w1     = (const float*)d_in[3];
    const float* bias1  = (const float*)d_in[4];
    const float* cmaps2 = (const float*)d_in[5];
    const float* w2     = (const float*)d_in[6];
    const float* bias2  = (const float*)d_in[7];
    const float* cmaps3 = (const float*)d_in[8];
    const float* w3     = (const float*)d_in[9];
    float* out = (float*)d_out;

    float* xT     = (float*)d_ws;                         // IN*B      = 131072
    float* l0     = xT    + (size_t)IN_ * B_;             // B*IN      = 131072
    float* l0T    = l0    + (size_t)B_ * IN_;             // IN*B      = 131072
    float* out1T  = l0T   + (size_t)IN_ * B_;             // C*(S1+1)*B = 262144
    float* out1RM = out1T + (size_t)C_ * (S1_ + 1) * B_;  // C*B*(S1+1) = 262144
    // layer-3 inputs alias the l0 region (l0/l0T dead after layer-1 kernel)
    float* out2T  = l0;                                   // C*(S2+1)*B = 65536
    float* out2RM = l0T;                                  // C*B*(S2+1) = 65536

    float* logits = out;
    float* nw1 = out + (size_t)B_ * C_;
    float* nw2 = nw1 + (size_t)C_ * S1_ * K_ * IN_;
    float* nw3 = nw2 + (size_t)C_ * S2_ * K_ * (S1_ + 1);

    prep_kernel<<<dim3(128), dim3(256), 0, stream>>>(x, xT, l0, l0T);

    // layer 1: lg = l0 (c-stride 0)
    layer_kernel<<<dim3(C_ * S1_), dim3(256), 0, stream>>>(
        xT, l0T, l0, 0L, 0L, target, cmaps1, w1, nw1,
        out1T, out1RM, bias1, S1_, IN_, 0);

    // layer 2: lg = out1 [c][b][S1+1]
    layer_kernel<<<dim3(C_ * S2_), dim3(256), 0, stream>>>(
        xT, out1T, out1RM, (long)(S1_ + 1) * B_, (long)B_ * (S1_ + 1), target, cmaps2, w2, nw2,
        out2T, out2RM, bias2, S2_, S1_ + 1, 0);

    // layer 3: lg = out2 [c][b][S2+1]; writes logits
    layer_kernel<<<dim3(C_), dim3(256), 0, stream>>>(
        xT, out2T, out2RM, (long)(S2_ + 1) * B_, (long)B_ * (S2_ + 1), target, cmaps3, w3, nw3,
        nullptr, logits, nullptr, 1, S2_ + 1, 1);
}

// Round 3
// 175.249 us; speedup vs baseline: 2.0196x; 1.1657x over previous
//
#include <hip/hip_runtime.h>
#include <math.h>

#define B_   256
#define IN_  512
#define C_   4
#define M_   6
#define K_   64
#define S1_  255
#define S2_  63
#define WCH  32    // w-chunk width (k per chunk)

#define NBLK1 (C_ * S1_)                 // 1020
#define NBLK2 (C_ * S2_)                 // 252
#define NBLK3 (C_)                       // 4
#define NBLK_ALL (NBLK1 + NBLK2 + NBLK3) // 1276
#define WIN_TOTAL (NBLK_ALL * K_)        // 81664

#define LMIN_ (-6.906754778648554f)
#define LMAX_ ( 6.906754778648554f)
#define LR_   0.001f
#define WCLIP_ 5.0f

__device__ __forceinline__ float clampf(float v, float lo, float hi) {
    return fminf(fmaxf(v, lo), hi);
}

// One-time prep: xT[i][b], l0[b][i], l0T[i][b]; init winner buf to -1.
__global__ __launch_bounds__(256) void prep_kernel(const float* __restrict__ x,
                                                   float* __restrict__ xT,
                                                   float* __restrict__ l0,
                                                   float* __restrict__ l0T,
                                                   int* __restrict__ win_buf) {
    __shared__ float tx_[32][33];
    __shared__ float tl_[32][33];
    const int i0 = (blockIdx.x & 15) * 32;   // IN/32 = 16 tiles
    const int b0 = (blockIdx.x >> 4) * 32;   // B/32  = 8 tiles
    const int tx = threadIdx.x & 31;
    const int ty = threadIdx.x >> 5;         // 0..7
#pragma unroll
    for (int r = 0; r < 4; ++r) {
        int bb = b0 + ty + 8 * r;
        int ii = i0 + tx;
        float xv = x[(size_t)bb * IN_ + ii];
        float xc = clampf(xv, 0.001f, 0.999f);
        float lv = (ii == 0) ? 0.0f : logf(xc / (1.0f - xc));
        l0[(size_t)bb * IN_ + ii] = lv;
        tx_[ty + 8 * r][tx] = xv;
        tl_[ty + 8 * r][tx] = lv;
    }
    __syncthreads();
#pragma unroll
    for (int r = 0; r < 4; ++r) {
        int ii = i0 + ty + 8 * r;
        int bb = b0 + tx;
        xT[(size_t)ii * B_ + bb]  = tx_[tx][ty + 8 * r];
        l0T[(size_t)ii * B_ + bb] = tl_[tx][ty + 8 * r];
    }
    int gid = blockIdx.x * 256 + threadIdx.x;       // 0..32767
    for (int i = gid; i < WIN_TOTAL; i += 128 * 256) win_buf[i] = -1;
}

// Routing for ALL layers: one block per (c,s) row-group; thread = batch b.
__global__ __launch_bounds__(256) void route_kernel(
    const float* __restrict__ xT,       // [IN][B]
    const float* __restrict__ cmaps1,   // [C][S1][M][IN]
    const float* __restrict__ cmaps2,
    const float* __restrict__ cmaps3,
    int* __restrict__ idx_buf,          // [NBLK_ALL][B]
    int* __restrict__ win_buf)          // [NBLK_ALL][K]
{
    const int bid = blockIdx.x;
    const float* cmp;
    if (bid < NBLK1)              cmp = cmaps1 + (size_t)bid * M_ * IN_;
    else if (bid < NBLK1 + NBLK2) cmp = cmaps2 + (size_t)(bid - NBLK1) * M_ * IN_;
    else                          cmp = cmaps3 + (size_t)(bid - NBLK1 - NBLK2) * M_ * IN_;

    const int b = threadIdx.x;
    float acc[M_];
#pragma unroll
    for (int m = 0; m < M_; ++m) acc[m] = 0.0f;

    for (int k = 0; k < IN_; k += 8) {
        float xv[8];
#pragma unroll
        for (int j = 0; j < 8; ++j) xv[j] = xT[(size_t)(k + j) * B_ + b];  // coalesced, L2-hot
#pragma unroll
        for (int j = 0; j < 8; ++j)
#pragma unroll
            for (int m = 0; m < M_; ++m)
                acc[m] = fmaf(cmp[(size_t)m * IN_ + k + j], xv[j], acc[m]); // uniform -> s_load
    }
    int myidx = 0;
#pragma unroll
    for (int m = 0; m < M_; ++m) myidx |= (acc[m] > 0.0f) ? (1 << m) : 0;

    idx_buf[(size_t)bid * B_ + b] = myidx;
    atomicMax(&win_buf[(size_t)bid * K_ + myidx], b);   // last-b-wins == max b
}

// One block per (c,s); 256 threads; thread = batch row b. Phases B + D only.
__global__ __launch_bounds__(256) void layer_kernel(
    const float* __restrict__ lgT,     // lgT[c*lgT_sc + k*B + b]
    const float* __restrict__ lgRM,    // lg[c*lg_sc + b*Din + k]
    long lgT_sc, long lg_sc,
    const int* __restrict__ target,
    const float* __restrict__ w,       // [C][S][K][Din]
    float* __restrict__ nw,
    float* __restrict__ onextT,        // [c][S+1][b]  (null if last)
    float* __restrict__ onextRM,       // [c][b][S+1], or logits[b][c] if last
    const float* __restrict__ bias,    // [1,1,C] or null
    const int* __restrict__ idx_buf,   // [C*S][B] segment for this layer
    const int* __restrict__ win_buf,   // [C*S][K] segment for this layer
    int S, int Din, int is_last)
{
    __shared__ float wl[2][K_][WCH + 1];
    __shared__ float diff_s[B_];
    __shared__ int   win_s[K_];

    const int c   = blockIdx.x / S;
    const int s   = blockIdx.x % S;
    const int tid = threadIdx.x;
    const int b   = tid;

    if (tid < K_) win_s[tid] = win_buf[(size_t)blockIdx.x * K_ + tid];
    const int myidx = idx_buf[(size_t)blockIdx.x * B_ + b];

    // ---------- Phase B: out = clip( w[c,s,idx[b],:] . lg[b,:,c] ) ----------
    const float* wp   = w   + (size_t)blockIdx.x * K_ * Din;
    const float* lgTc = lgT + (size_t)c * lgT_sc;
    const int NT = Din / WCH;

    // stage chunk t: 64 rows x 32 cols = 512 float4 = 2/thread
#define STAGE(buf, t)                                                          \
    {                                                                          \
        const float* src = wp + (size_t)(t) * WCH;                             \
        _Pragma("unroll")                                                      \
        for (int j = 0; j < 2; ++j) {                                          \
            int f   = tid + 256 * j;                                           \
            int row = f >> 3;                                                  \
            int kq  = (f & 7) << 2;                                            \
            const float4 v = *(const float4*)(src + (size_t)row * Din + kq);   \
            wl[buf][row][kq + 0] = v.x;                                        \
            wl[buf][row][kq + 1] = v.y;                                        \
            wl[buf][row][kq + 2] = v.z;                                        \
            wl[buf][row][kq + 3] = v.w;                                        \
        }                                                                      \
    }

    STAGE(0, 0)
    __syncthreads();

    float dot = 0.0f;
    for (int t = 0; t < NT; ++t) {
        const int cur = t & 1;
        if (t + 1 < NT) STAGE(cur ^ 1, t + 1)
#pragma unroll
        for (int kk = 0; kk < WCH; ++kk)
            dot = fmaf(wl[cur][myidx][kk], lgTc[(size_t)(t * WCH + kk) * B_ + b], dot);
        __syncthreads();
    }

    float outv = clampf(dot, LMIN_, LMAX_);
    if (is_last) {
        onextRM[(size_t)b * C_ + c] = outv;                          // logits[b][c]
    } else {
        onextT[((size_t)c * (S + 1) + (s + 1)) * B_ + b] = outv;     // coalesced
        onextRM[((size_t)c * B_ + b) * (size_t)(S + 1) + (s + 1)] = outv;
        if (s == 0) {
            float bv = bias[c];
            onextT[((size_t)c * (S + 1)) * B_ + b] = bv;
            onextRM[((size_t)c * B_ + b) * (size_t)(S + 1)] = bv;
        }
    }
    float tg = (target[b] == c) ? 1.0f : 0.0f;
    diff_s[b] = 1.0f / (1.0f + expf(-outv)) - tg;
    __syncthreads();

    // ---------- Phase D: nw = clip(w - LR*diff[b*]*lg[b*,:], +-WCLIP) ----------
    float* nwp = nw + (size_t)blockIdx.x * K_ * Din;
    const float* lgc = lgRM + (size_t)c * lg_sc;
    const int qpr   = Din >> 2;
    const int qprs  = (Din == 512) ? 7 : (Din == 256) ? 6 : 4;
    const int quads = K_ * qpr;
    for (int q = tid; q < quads; q += 256) {
        int row = q >> qprs;
        int col = (q & (qpr - 1)) << 2;
        float4 wv = *(const float4*)(wp + (size_t)row * Din + col);
        int bw = win_s[row];
        if (bw >= 0) {
            float d = LR_ * diff_s[bw];
            const float4 lv = *(const float4*)(lgc + (size_t)bw * Din + col);
            wv.x = clampf(wv.x - d * lv.x, -WCLIP_, WCLIP_);
            wv.y = clampf(wv.y - d * lv.y, -WCLIP_, WCLIP_);
            wv.z = clampf(wv.z - d * lv.z, -WCLIP_, WCLIP_);
            wv.w = clampf(wv.w - d * lv.w, -WCLIP_, WCLIP_);
        }
        *(float4*)(nwp + (size_t)row * Din + col) = wv;
    }
#undef STAGE
}

extern "C" void kernel_launch(void* const* d_in, const int* in_sizes, int n_in,
                              void* d_out, int out_size, void* d_ws, size_t ws_size,
                              hipStream_t stream) {
    const float* x      = (const float*)d_in[0];
    const int*   target = (const int*)  d_in[1];
    const float* cmaps1 = (const float*)d_in[2];
    const float* w1     = (const float*)d_in[3];
    const float* bias1  = (const float*)d_in[4];
    const float* cmaps2 = (const float*)d_in[5];
    const float* w2     = (const float*)d_in[6];
    const float* bias2  = (const float*)d_in[7];
    const float* cmaps3 = (const float*)d_in[8];
    const float* w3     = (const float*)d_in[9];
    float* out = (float*)d_out;

    float* xT     = (float*)d_ws;                         // IN*B
    float* l0     = xT    + (size_t)IN_ * B_;             // B*IN
    float* l0T    = l0    + (size_t)B_ * IN_;             // IN*B
    float* out1T  = l0T   + (size_t)IN_ * B_;             // C*(S1+1)*B
    float* out1RM = out1T + (size_t)C_ * (S1_ + 1) * B_;  // C*B*(S1+1)
    int*   idx_buf = (int*)(out1RM + (size_t)C_ * B_ * (S1_ + 1));  // NBLK_ALL*B
    int*   win_buf = idx_buf + (size_t)NBLK_ALL * B_;               // NBLK_ALL*K
    // layer-3 inputs alias the l0 region (dead after layer-1 kernel)
    float* out2T  = l0;
    float* out2RM = l0T;

    float* logits = out;
    float* nw1 = out + (size_t)B_ * C_;
    float* nw2 = nw1 + (size_t)C_ * S1_ * K_ * IN_;
    float* nw3 = nw2 + (size_t)C_ * S2_ * K_ * (S1_ + 1);

    prep_kernel<<<dim3(128), dim3(256), 0, stream>>>(x, xT, l0, l0T, win_buf);

    route_kernel<<<dim3(NBLK_ALL), dim3(256), 0, stream>>>(
        xT, cmaps1, cmaps2, cmaps3, idx_buf, win_buf);

    // layer 1: lg = l0 (c-stride 0)
    layer_kernel<<<dim3(NBLK1), dim3(256), 0, stream>>>(
        l0T, l0, 0L, 0L, target, w1, nw1,
        out1T, out1RM, bias1, idx_buf, win_buf, S1_, IN_, 0);

    // layer 2: lg = out1 [c][b][S1+1]
    layer_kernel<<<dim3(NBLK2), dim3(256), 0, stream>>>(
        out1T, out1RM, (long)(S1_ + 1) * B_, (long)B_ * (S1_ + 1), target, w2, nw2,
        out2T, out2RM, bias2, idx_buf + (size_t)NBLK1 * B_, win_buf + (size_t)NBLK1 * K_,
        S2_, S1_ + 1, 0);

    // layer 3: lg = out2 [c][b][S2+1]; writes logits
    layer_kernel<<<dim3(NBLK3), dim3(256), 0, stream>>>(
        out2T, out2RM, (long)(S2_ + 1) * B_, (long)B_ * (S2_ + 1), target, w3, nw3,
        nullptr, logits, nullptr, idx_buf + (size_t)(NBLK1 + NBLK2) * B_,
        win_buf + (size_t)(NBLK1 + NBLK2) * K_, 1, S2_ + 1, 1);
}